// Round 1
// baseline (713.403 us; speedup 1.0000x reference)
//
#include <hip/hip_runtime.h>

typedef __attribute__((ext_vector_type(8))) short short8;
typedef __attribute__((ext_vector_type(4))) float f32x4;

#define ALPHA_F 0.05f

static __device__ __forceinline__ unsigned short f2bf(float f) {
  unsigned int u = __float_as_uint(f);
  unsigned int r = (u + 0x7fffu + ((u >> 16) & 1u)) >> 16;
  return (unsigned short)r;
}

static __device__ __forceinline__ void gld16(const void* g, void* l) {
  __builtin_amdgcn_global_load_lds((const __attribute__((address_space(1))) void*)g,
                                   (__attribute__((address_space(3))) void*)l, 16, 0, 0);
}

// ---------------- K1: adjacency prep: normalize (i,j,k) + self-loop, convert all to bf16 ----------------
__global__ __launch_bounds__(256) void prep_adj(const float* __restrict__ ar,
    const float* __restrict__ ai, const float* __restrict__ aj, const float* __restrict__ ak,
    unsigned short* __restrict__ Abf)
{
  const int bid = blockIdx.x;
  const int p = bid >> 12;        // which matrix 0..3
  const int row = bid & 4095;
  const float* src = (p == 0) ? ar : (p == 1) ? ai : (p == 2) ? aj : ak;
  const float4* r4 = (const float4*)(src + ((size_t)row << 12));
  ushort4* dst = (ushort4*)(Abf + (((size_t)p << 12) + (size_t)row) * 4096);

  if (p == 0) {
    for (int i = threadIdx.x; i < 1024; i += 256) {
      float4 v = r4[i];
      dst[i] = make_ushort4(f2bf(v.x), f2bf(v.y), f2bf(v.z), f2bf(v.w));
    }
  } else {
    float4 vals[4];
    float s = 0.f;
    #pragma unroll
    for (int it = 0; it < 4; ++it) {
      float4 v = r4[threadIdx.x + it * 256];
      vals[it] = v;
      s += v.x + v.y + v.z + v.w;
    }
    #pragma unroll
    for (int off = 32; off >= 1; off >>= 1) s += __shfl_down(s, off, 64);
    __shared__ float red[4];
    if ((threadIdx.x & 63) == 0) red[threadIdx.x >> 6] = s;
    __syncthreads();
    const float inv = 1.0f / (red[0] + red[1] + red[2] + red[3] + 1.0f); // +1 self loop
    #pragma unroll
    for (int it = 0; it < 4; ++it) {
      const int i = threadIdx.x + it * 256;
      float4 v = vals[it];
      const int base = i << 2;
      if (row - base >= 0 && row - base < 4) ((float*)&v)[row - base] += 1.0f; // self loop
      dst[i] = make_ushort4(f2bf(v.x * inv), f2bf(v.y * inv), f2bf(v.z * inv), f2bf(v.w * inv));
    }
  }
}

// ---------------- K2: pack x [b,c,n,t] f32 -> XT [col=c*24+b*12+t][n] bf16 ----------------
__global__ __launch_bounds__(256) void pack_x(const float* __restrict__ x,
                                              unsigned short* __restrict__ XT)
{
  const int o = blockIdx.x * 256 + threadIdx.x;   // col*4096 + n, total 1572864
  const int n = o & 4095;
  const int col = o >> 12;
  const int c = col / 24;
  const int rr = col - c * 24;
  const int b = rr / 12;
  const int t = rr - b * 12;
  const float v = x[(((size_t)(b * 16 + c) << 12) | (size_t)n) * 12 + t];
  XT[o] = f2bf(v);
}

// ---------------- K3: GEMM  C[16384][384] = Abf[16384][4096] * XT[384][4096]^T ----------------
#define GBM 128
#define GBN 96
#define GBK 32

__global__ __launch_bounds__(256, 2) void gemm_bt(const unsigned short* __restrict__ A,
    const unsigned short* __restrict__ BT, float* __restrict__ C)
{
  __shared__ __align__(16) unsigned short As[2][GBM * GBK];
  __shared__ __align__(16) unsigned short Bs[2][GBN * GBK];
  const int tid = threadIdx.x;
  const int bx = blockIdx.x;
  const int ntile = bx & 3;       // 4 N-tiles of 96
  const int mtile = bx >> 2;      // 128 M-tiles of 128
  const int brow0 = mtile * GBM;
  const int bcol0 = ntile * GBN;
  const int lane = tid & 63;
  const int w = tid >> 6;
  const int wr = w >> 1, wc = w & 1;   // 2x2 waves, each 64(M) x 48(N)

  f32x4 acc[4][3];
  #pragma unroll
  for (int m = 0; m < 4; ++m)
    #pragma unroll
    for (int n = 0; n < 3; ++n) acc[m][n] = (f32x4){0.f, 0.f, 0.f, 0.f};

  auto stage = [&](int buf, int kt) {
    const int k0 = kt * GBK;
    #pragma unroll
    for (int iss = 0; iss < 2; ++iss) {
      const int idx = iss * 256 + tid;
      {
        const int row = idx >> 2, kc = (idx & 3) << 3;
        gld16(A + (((size_t)(brow0 + row)) << 12) + (size_t)(k0 + kc), &As[buf][idx << 3]);
      }
      if (idx < (GBN * GBK) / 8) {  // 384 chunks; wave-uniform predicate
        const int row = idx >> 2, kc = (idx & 3) << 3;
        gld16(BT + (((size_t)(bcol0 + row)) << 12) + (size_t)(k0 + kc), &Bs[buf][idx << 3]);
      }
    }
  };

  stage(0, 0);
  const int NK = 4096 / GBK;   // 128
  for (int kt = 0; kt < NK; ++kt) {
    const int buf = kt & 1;
    __syncthreads();                       // drains vmcnt: staged tile ready
    if (kt + 1 < NK) stage(buf ^ 1, kt + 1);
    const int kb = (lane >> 4) << 3;       // k offset per lane group (8 contiguous k)
    const int rl0 = wr * 64 + (lane & 15);
    short8 af[4];
    #pragma unroll
    for (int m = 0; m < 4; ++m)
      af[m] = *(const short8*)&As[buf][(rl0 + m * 16) * GBK + kb];
    const int cl0 = wc * 48 + (lane & 15);
    short8 bfr[3];
    #pragma unroll
    for (int n = 0; n < 3; ++n)
      bfr[n] = *(const short8*)&Bs[buf][(cl0 + n * 16) * GBK + kb];
    #pragma unroll
    for (int m = 0; m < 4; ++m)
      #pragma unroll
      for (int n = 0; n < 3; ++n)
        acc[m][n] = __builtin_amdgcn_mfma_f32_16x16x32_bf16(af[m], bfr[n], acc[m][n], 0, 0, 0);
  }

  // epilogue: C/D layout col = lane&15, row = (lane>>4)*4 + e  (verified m89)
  #pragma unroll
  for (int m = 0; m < 4; ++m) {
    const int gr0 = brow0 + wr * 64 + m * 16 + ((lane >> 4) << 2);
    #pragma unroll
    for (int n = 0; n < 3; ++n) {
      const int gc = bcol0 + wc * 48 + n * 16 + (lane & 15);
      #pragma unroll
      for (int e = 0; e < 4; ++e)
        C[(size_t)(gr0 + e) * 384 + gc] = acc[m][n][e];
    }
  }
}

// ---------------- K4: Hamilton-sign combine: h = a*x + (1-a)*sum_p s*P_p ; emit H f32 + XT bf16 ----------------
__global__ __launch_bounds__(256) void combine_k(const float* __restrict__ P,
    const float* __restrict__ x, float* __restrict__ H, unsigned short* __restrict__ XT,
    const int writeXT)
{
  __shared__ unsigned short T[64][72];
  const int n0 = (blockIdx.x / 6) << 6;
  const int c0 = (blockIdx.x % 6) << 6;
  static const int   sigma_t[4][4] = {{0,1,2,3},{1,0,3,2},{2,3,0,1},{3,2,1,0}};
  static const float sgn_t[4][4]   = {{1,-1,-1,-1},{1,1,1,-1},{1,-1,1,1},{1,1,-1,1}};
  #pragma unroll
  for (int r = 0; r < 16; ++r) {
    const int idx = r * 256 + threadIdx.x;
    const int ln = idx >> 6, lc = idx & 63;
    const int n = n0 + ln, col = c0 + lc;
    const int q = col / 96;
    const int cm = col - q * 96;
    float acc = 0.f;
    #pragma unroll
    for (int p = 0; p < 4; ++p)
      acc += sgn_t[q][p] * P[((size_t)p * 4096 + (size_t)n) * 384 + (size_t)(sigma_t[q][p] * 96 + cm)];
    const int c = col / 24, rr = col - c * 24;
    const int b = rr / 12, t = rr - b * 12;
    const float xv = x[(((size_t)(b * 16 + c) << 12) | (size_t)n) * 12 + t];
    const float h = ALPHA_F * xv + (1.f - ALPHA_F) * acc;
    H[(size_t)n * 384 + col] = h;
    T[lc][ln] = f2bf(h);
  }
  if (writeXT) {
    __syncthreads();
    #pragma unroll
    for (int r = 0; r < 16; ++r) {
      const int idx = r * 256 + threadIdx.x;
      const int lc = idx >> 6, ln = idx & 63;
      XT[((size_t)(c0 + lc) << 12) + (size_t)(n0 + ln)] = T[lc][ln];
    }
  }
}

// ---------------- K5: final einsum with hamilton(weight) ----------------
__global__ __launch_bounds__(256) void final_k(const float* __restrict__ x,
    const float* __restrict__ H1, const float* __restrict__ H2,
    const float* __restrict__ wgt, float* __restrict__ out)
{
  __shared__ float Hm[3][16][16];
  static const int   comp_t[4][4] = {{0,1,2,3},{1,0,3,2},{2,3,0,1},{3,2,1,0}};
  static const float hsgn_t[4][4] = {{1,-1,-1,-1},{1,1,-1,1},{1,1,1,-1},{1,-1,1,1}};
  for (int idx = threadIdx.x; idx < 768; idx += 256) {
    const int k = idx >> 8, i = (idx >> 4) & 15, j = idx & 15;
    const int J = j >> 2, I = i >> 2, a = i & 3, jj = j & 3;
    Hm[k][i][j] = hsgn_t[J][I] * wgt[(k * 4 + a) * 16 + comp_t[J][I] * 4 + jj];
  }
  __syncthreads();
  const int o = blockIdx.x * 256 + threadIdx.x;  // 98304 points (b,n,t)
  const int t = o % 12;
  const int nb = o / 12;
  const int n = nb & 4095;
  const int b = nb >> 12;
  float v[3][16];
  #pragma unroll
  for (int i = 0; i < 16; ++i)
    v[0][i] = x[((((size_t)(b * 16 + i)) << 12) | (size_t)n) * 12 + t];
  const int colbase = b * 12 + t;
  #pragma unroll
  for (int i = 0; i < 16; ++i) {
    const size_t hidx = (size_t)n * 384 + (size_t)(i * 24 + colbase);
    v[1][i] = H1[hidx];
    v[2][i] = H2[hidx];
  }
  #pragma unroll
  for (int j = 0; j < 16; ++j) {
    float acc = 0.f;
    #pragma unroll
    for (int k = 0; k < 3; ++k)
      #pragma unroll
      for (int i = 0; i < 16; ++i)
        acc += v[k][i] * Hm[k][i][j];
    out[((((size_t)(b * 16 + j)) << 12) | (size_t)n) * 12 + t] = acc;
  }
}

extern "C" void kernel_launch(void* const* d_in, const int* in_sizes, int n_in,
                              void* d_out, int out_size, void* d_ws, size_t ws_size,
                              hipStream_t stream)
{
  const float* x   = (const float*)d_in[0];
  const float* ar  = (const float*)d_in[1];
  const float* ai  = (const float*)d_in[2];
  const float* aj  = (const float*)d_in[3];
  const float* ak  = (const float*)d_in[4];
  const float* wgt = (const float*)d_in[5];
  float* out = (float*)d_out;

  char* ws = (char*)d_ws;
  unsigned short* Abf = (unsigned short*)(ws);                  // 4*4096*4096*2 = 134217728
  unsigned short* XT0 = (unsigned short*)(ws + 134217728);      // 384*4096*2    =   3145728
  unsigned short* XT1 = (unsigned short*)(ws + 137363456);      //                  3145728
  float*          P   = (float*)(ws + 140509184);               // 16384*384*4   =  25165824
  float*          H1  = (float*)(ws + 165675008);               // 4096*384*4    =   6291456
  float*          H2  = (float*)(ws + 171966464);               //                  6291456
  // total 178257920 bytes

  prep_adj<<<dim3(16384), dim3(256), 0, stream>>>(ar, ai, aj, ak, Abf);
  pack_x<<<dim3(6144), dim3(256), 0, stream>>>(x, XT0);
  gemm_bt<<<dim3(512), dim3(256), 0, stream>>>(Abf, XT0, P);
  combine_k<<<dim3(384), dim3(256), 0, stream>>>(P, x, H1, XT1, 1);
  gemm_bt<<<dim3(512), dim3(256), 0, stream>>>(Abf, XT1, P);
  combine_k<<<dim3(384), dim3(256), 0, stream>>>(P, x, H2, XT1, 0);
  final_k<<<dim3(384), dim3(256), 0, stream>>>(x, H1, H2, wgt, out);
}

// Round 2
// 481.171 us; speedup vs baseline: 1.4826x; 1.4826x over previous
//
#include <hip/hip_runtime.h>

typedef __attribute__((ext_vector_type(8))) short short8;
typedef __attribute__((ext_vector_type(4))) float f32x4;

#define ALPHA_F 0.05f

static __device__ __forceinline__ unsigned short f2bf(float f) {
  unsigned int u = __float_as_uint(f);
  unsigned int r = (u + 0x7fffu + ((u >> 16) & 1u)) >> 16;
  return (unsigned short)r;
}

static __device__ __forceinline__ void gld16(const void* g, void* l) {
  __builtin_amdgcn_global_load_lds((const __attribute__((address_space(1))) void*)g,
                                   (__attribute__((address_space(3))) void*)l, 16, 0, 0);
}

// ---------------- K1: adjacency prep: normalize (i,j,k) + self-loop, convert all to bf16 ----------------
__global__ __launch_bounds__(256) void prep_adj(const float* __restrict__ ar,
    const float* __restrict__ ai, const float* __restrict__ aj, const float* __restrict__ ak,
    unsigned short* __restrict__ Abf)
{
  const int bid = blockIdx.x;
  const int p = bid >> 12;        // which matrix 0..3
  const int row = bid & 4095;
  const float* src = (p == 0) ? ar : (p == 1) ? ai : (p == 2) ? aj : ak;
  const float4* r4 = (const float4*)(src + ((size_t)row << 12));
  ushort4* dst = (ushort4*)(Abf + (((size_t)p << 12) + (size_t)row) * 4096);

  if (p == 0) {
    for (int i = threadIdx.x; i < 1024; i += 256) {
      float4 v = r4[i];
      dst[i] = make_ushort4(f2bf(v.x), f2bf(v.y), f2bf(v.z), f2bf(v.w));
    }
  } else {
    float4 vals[4];
    float s = 0.f;
    #pragma unroll
    for (int it = 0; it < 4; ++it) {
      float4 v = r4[threadIdx.x + it * 256];
      vals[it] = v;
      s += v.x + v.y + v.z + v.w;
    }
    #pragma unroll
    for (int off = 32; off >= 1; off >>= 1) s += __shfl_down(s, off, 64);
    __shared__ float red[4];
    if ((threadIdx.x & 63) == 0) red[threadIdx.x >> 6] = s;
    __syncthreads();
    const float inv = 1.0f / (red[0] + red[1] + red[2] + red[3] + 1.0f); // +1 self loop
    #pragma unroll
    for (int it = 0; it < 4; ++it) {
      const int i = threadIdx.x + it * 256;
      float4 v = vals[it];
      const int base = i << 2;
      if (row - base >= 0 && row - base < 4) ((float*)&v)[row - base] += 1.0f; // self loop
      dst[i] = make_ushort4(f2bf(v.x * inv), f2bf(v.y * inv), f2bf(v.z * inv), f2bf(v.w * inv));
    }
  }
}

// ---------------- K2: pack x -> XT0 bf16 [col][n], and init H1,H2 = alpha*x (f32 [n][384]) ----------------
__global__ __launch_bounds__(256) void pack_x2(const float* __restrict__ x,
    unsigned short* __restrict__ XT0, float* __restrict__ H1, float* __restrict__ H2)
{
  __shared__ float tile[3072];
  const int nt = blockIdx.x & 15;          // 16 n-tiles of 256
  const int c  = (blockIdx.x >> 4) & 15;
  const int b  = blockIdx.x >> 8;
  const int n0 = nt << 8;
  const int col0 = c * 24 + b * 12;
  const size_t base = ((size_t)(b * 16 + c) * 4096 + n0) * 12;
  #pragma unroll
  for (int it = 0; it < 12; ++it) {
    const int idx = it * 256 + threadIdx.x;
    tile[idx] = x[base + idx];
  }
  __syncthreads();
  // XT0 writes: coalesced along n
  #pragma unroll
  for (int it = 0; it < 12; ++it) {
    const int idx = it * 256 + threadIdx.x;
    const int t = idx >> 8, i = idx & 255;
    XT0[(size_t)(col0 + t) * 4096 + (n0 + i)] = f2bf(tile[i * 12 + t]);
  }
  // H init: 12-float contiguous runs per row
  #pragma unroll
  for (int it = 0; it < 12; ++it) {
    const int idx = it * 256 + threadIdx.x;
    const int i = idx / 12, t = idx - i * 12;
    const float v = ALPHA_F * tile[i * 12 + t];
    const size_t o = (size_t)(n0 + i) * 384 + (col0 + t);
    H1[o] = v;
    H2[o] = v;
  }
}

// ---------------- K3: GEMM+combine: for block (p, n-tile): S = A_p[64 rows] * XT^T (all 384 cols);
//                  epilogue atomically adds 0.95*sgn[q][p]*S[:, s-block] into H[:, q-block], q = s^p ----------
#define SBM 64
#define SBN 384
#define SBK 64

__global__ __launch_bounds__(512, 2) void gemm_s(const unsigned short* __restrict__ A,
    const unsigned short* __restrict__ BT, float* __restrict__ H)
{
  __shared__ __align__(16) unsigned short As[2][SBM * SBK];   // 16 KB
  __shared__ __align__(16) unsigned short Bs[2][SBN * SBK];   // 96 KB
  const int tid = threadIdx.x;
  const int p  = blockIdx.x >> 6;
  const int n0 = (blockIdx.x & 63) << 6;
  const int lane = tid & 63;
  const int w = tid >> 6;
  const int wm = w >> 2;      // M half (32 rows)
  const int ws = w & 3;       // N quarter (96 cols) == source component block s

  f32x4 acc[2][6];
  #pragma unroll
  for (int m = 0; m < 2; ++m)
    #pragma unroll
    for (int n = 0; n < 6; ++n) acc[m][n] = (f32x4){0.f, 0.f, 0.f, 0.f};

  // stage: LDS[row][ch] = G[row][ch ^ (row&7)]  (source-side swizzle; LDS dest linear)
  auto stage = [&](int buf, int kt) {
    const int k0 = kt << 6;
    #pragma unroll
    for (int it = 0; it < 7; ++it) {
      const int idx = it * 512 + tid;
      if (it == 0) {      // A: 512 chunks of 16B
        const int row = idx >> 3, ch = idx & 7;
        const int chs = ch ^ (row & 7);
        gld16(A + (((size_t)(p * 4096 + n0 + row)) << 12) + (size_t)(k0 + chs * 8),
              (unsigned short*)As[buf] + idx * 8);
      } else {            // B: 3072 chunks
        const int bidx = idx - 512;
        const int row = bidx >> 3, ch = bidx & 7;
        const int chs = ch ^ (row & 7);
        gld16(BT + ((size_t)row << 12) + (size_t)(k0 + chs * 8),
              (unsigned short*)Bs[buf] + bidx * 8);
      }
    }
  };

  stage(0, 0);
  const int l15 = lane & 15, lk = lane >> 4;
  for (int kt = 0; kt < 64; ++kt) {
    const int buf = kt & 1;
    __syncthreads();
    if (kt + 1 < 64) stage(buf ^ 1, kt + 1);
    short8 af[2][2], bf[6][2];
    #pragma unroll
    for (int m = 0; m < 2; ++m) {
      const int row = wm * 32 + m * 16 + l15;
      #pragma unroll
      for (int ks = 0; ks < 2; ++ks) {
        const int ck = (lk + ks * 4) ^ (row & 7);
        af[m][ks] = *(const short8*)&As[buf][row * 64 + ck * 8];
      }
    }
    #pragma unroll
    for (int n = 0; n < 6; ++n) {
      const int row = ws * 96 + n * 16 + l15;
      #pragma unroll
      for (int ks = 0; ks < 2; ++ks) {
        const int ck = (lk + ks * 4) ^ (row & 7);
        bf[n][ks] = *(const short8*)&Bs[buf][row * 64 + ck * 8];
      }
    }
    #pragma unroll
    for (int ks = 0; ks < 2; ++ks)
      #pragma unroll
      for (int m = 0; m < 2; ++m)
        #pragma unroll
        for (int n = 0; n < 6; ++n)
          acc[m][n] = __builtin_amdgcn_mfma_f32_16x16x32_bf16(af[m][ks], bf[n][ks], acc[m][n], 0, 0, 0);
  }

  // epilogue: q = s ^ p (sigma[q][p] == q^p), C/D layout col=lane&15, row=(lane>>4)*4+e
  static const float sgn_t[4][4] = {{1,-1,-1,-1},{1,1,1,-1},{1,-1,1,1},{1,1,-1,1}};
  const int q = ws ^ p;
  const float coef = (1.0f - ALPHA_F) * sgn_t[q][p];
  #pragma unroll
  for (int m = 0; m < 2; ++m) {
    const int nr0 = n0 + wm * 32 + m * 16 + ((lane >> 4) << 2);
    #pragma unroll
    for (int n = 0; n < 6; ++n) {
      const int cc = q * 96 + n * 16 + (lane & 15);
      #pragma unroll
      for (int e = 0; e < 4; ++e)
        atomicAdd(&H[(size_t)(nr0 + e) * 384 + cc], coef * acc[m][n][e]);
    }
  }
}

// ---------------- K4: pack H (f32 [n][384]) -> XT (bf16 [col][n]) via LDS transpose ----------------
__global__ __launch_bounds__(256) void pack_h(const float* __restrict__ H,
                                              unsigned short* __restrict__ XT)
{
  __shared__ float T[64][65];
  const int n0 = (blockIdx.x / 6) << 6;
  const int c0 = (blockIdx.x % 6) << 6;
  #pragma unroll
  for (int it = 0; it < 16; ++it) {
    const int idx = it * 256 + threadIdx.x;
    const int r = idx >> 6, cl = idx & 63;
    T[r][cl] = H[(size_t)(n0 + r) * 384 + (c0 + cl)];
  }
  __syncthreads();
  #pragma unroll
  for (int it = 0; it < 16; ++it) {
    const int idx = it * 256 + threadIdx.x;
    const int cc = idx >> 6, rr = idx & 63;
    XT[(size_t)(c0 + cc) * 4096 + (n0 + rr)] = f2bf(T[rr][cc]);
  }
}

// ---------------- K5: final einsum with hamilton(weight) ----------------
__global__ __launch_bounds__(256) void final_k(const float* __restrict__ x,
    const float* __restrict__ H1, const float* __restrict__ H2,
    const float* __restrict__ wgt, float* __restrict__ out)
{
  __shared__ float Hm[3][16][16];
  static const int   comp_t[4][4] = {{0,1,2,3},{1,0,3,2},{2,3,0,1},{3,2,1,0}};
  static const float hsgn_t[4][4] = {{1,-1,-1,-1},{1,1,-1,1},{1,1,1,-1},{1,-1,1,1}};
  for (int idx = threadIdx.x; idx < 768; idx += 256) {
    const int k = idx >> 8, i = (idx >> 4) & 15, j = idx & 15;
    const int J = j >> 2, I = i >> 2, a = i & 3, jj = j & 3;
    Hm[k][i][j] = hsgn_t[J][I] * wgt[(k * 4 + a) * 16 + comp_t[J][I] * 4 + jj];
  }
  __syncthreads();
  const int o = blockIdx.x * 256 + threadIdx.x;  // 98304 points (b,n,t)
  const int t = o % 12;
  const int nb = o / 12;
  const int n = nb & 4095;
  const int b = nb >> 12;
  float v[3][16];
  #pragma unroll
  for (int i = 0; i < 16; ++i)
    v[0][i] = x[((((size_t)(b * 16 + i)) << 12) | (size_t)n) * 12 + t];
  const int colbase = b * 12 + t;
  #pragma unroll
  for (int i = 0; i < 16; ++i) {
    const size_t hidx = (size_t)n * 384 + (size_t)(i * 24 + colbase);
    v[1][i] = H1[hidx];
    v[2][i] = H2[hidx];
  }
  #pragma unroll
  for (int j = 0; j < 16; ++j) {
    float acc = 0.f;
    #pragma unroll
    for (int k = 0; k < 3; ++k)
      #pragma unroll
      for (int i = 0; i < 16; ++i)
        acc += v[k][i] * Hm[k][i][j];
    out[((((size_t)(b * 16 + j)) << 12) | (size_t)n) * 12 + t] = acc;
  }
}

extern "C" void kernel_launch(void* const* d_in, const int* in_sizes, int n_in,
                              void* d_out, int out_size, void* d_ws, size_t ws_size,
                              hipStream_t stream)
{
  const float* x   = (const float*)d_in[0];
  const float* ar  = (const float*)d_in[1];
  const float* ai  = (const float*)d_in[2];
  const float* aj  = (const float*)d_in[3];
  const float* ak  = (const float*)d_in[4];
  const float* wgt = (const float*)d_in[5];
  float* out = (float*)d_out;

  char* ws = (char*)d_ws;
  unsigned short* Abf = (unsigned short*)(ws);                  // 4*4096*4096*2 = 134217728
  unsigned short* XT0 = (unsigned short*)(ws + 134217728);      // 384*4096*2    =   3145728
  unsigned short* XT1 = (unsigned short*)(ws + 137363456);      //                  3145728
  float*          H1  = (float*)(ws + 140509184);               // 4096*384*4    =   6291456
  float*          H2  = (float*)(ws + 146800640);               //                  6291456
  // total 153092096 bytes

  prep_adj<<<dim3(16384), dim3(256), 0, stream>>>(ar, ai, aj, ak, Abf);
  pack_x2<<<dim3(512), dim3(256), 0, stream>>>(x, XT0, H1, H2);
  gemm_s<<<dim3(256), dim3(512), 0, stream>>>(Abf, XT0, H1);
  pack_h<<<dim3(384), dim3(256), 0, stream>>>(H1, XT1);
  gemm_s<<<dim3(256), dim3(512), 0, stream>>>(Abf, XT1, H2);
  final_k<<<dim3(384), dim3(256), 0, stream>>>(x, H1, H2, wgt, out);
}